// Round 1
// baseline (4020.913 us; speedup 1.0000x reference)
//
#include <hip/hip_runtime.h>
#include <cstdint>
#include <cstddef>

// Problem constants (fixed by harness)
#define B_  32
#define S_  64
#define T_  64
#define E_  512
#define H_  1024   // = 2E
#define VT_ 32000

using short8  = __attribute__((ext_vector_type(8))) short;
using floatx4 = __attribute__((ext_vector_type(4))) float;
using us4     = __attribute__((ext_vector_type(4))) unsigned short;

__device__ __forceinline__ unsigned short f2bf(float f) {
  unsigned int u = __builtin_bit_cast(unsigned int, f);
  u = u + 0x7fffu + ((u >> 16) & 1u);     // RNE
  return (unsigned short)(u >> 16);
}
__device__ __forceinline__ float sigf(float x) { return 1.f / (1.f + __expf(-x)); }

// async global->LDS, 16B per lane; LDS dest is wave-uniform base + lane*16
__device__ __forceinline__ void glds16(const void* g, void* l) {
  __builtin_amdgcn_global_load_lds(
      (const __attribute__((address_space(1))) unsigned int*)g,
      (__attribute__((address_space(3))) unsigned int*)l, 16, 0, 0);
}

// device-scope grid barrier (monotonic count, no reset within a launch).
// all 256 blocks are co-resident (1 block/CU, 72KB LDS < 160KB, capacity 2x).
__device__ __forceinline__ void gridbar(unsigned int* bar, unsigned int target) {
  __syncthreads();
  if (threadIdx.x == 0) {
    __threadfence();  // release (agent scope: L2 writeback for cross-XCD visibility)
    __hip_atomic_fetch_add(bar, 1u, __ATOMIC_RELAXED, __HIP_MEMORY_SCOPE_AGENT);
    while (__hip_atomic_load(bar, __ATOMIC_RELAXED, __HIP_MEMORY_SCOPE_AGENT) < target)
      __builtin_amdgcn_s_sleep(2);
    __threadfence();  // acquire (invalidate L1)
  }
  __syncthreads();
}

// ---------------- enc = concat(enc_emb[src], pos_emb[pos])  [B*S][1024] f32
__global__ void build_enc(const int* __restrict__ ss, const int* __restrict__ pp,
                          const float* __restrict__ enc_emb, const float* __restrict__ pos_emb,
                          float* __restrict__ enc) {
  int row = blockIdx.x, tid = threadIdx.x;
  int tok = ss[row], pos = pp[row];
  float2 a = *(const float2*)&enc_emb[(size_t)tok * E_ + tid * 2];
  float2 p = *(const float2*)&pos_emb[(size_t)pos * E_ + tid * 2];
  *(float2*)&enc[(size_t)row * 1024 + tid * 2]       = a;
  *(float2*)&enc[(size_t)row * 1024 + 512 + tid * 2] = p;
}

// ---------------- encmean[b][d] = mean over s
__global__ void enc_mean(const float* __restrict__ enc, float* __restrict__ em) {
  int b = blockIdx.x, tid = threadIdx.x;
  float4 acc = {0, 0, 0, 0};
  for (int s = 0; s < S_; ++s) {
    float4 v = *(const float4*)&enc[((size_t)b * S_ + s) * 1024 + tid * 4];
    acc.x += v.x; acc.y += v.y; acc.z += v.z; acc.w += v.w;
  }
  const float inv = 1.f / 64.f;
  acc.x *= inv; acc.y *= inv; acc.z *= inv; acc.w *= inv;
  *(float4*)&em[(size_t)b * 1024 + tid * 4] = acc;
}

// ---------------- h0 = encmean @ W_h0^T + b_h0 ; c0 = h0 (wave-per-output dot)
__global__ __launch_bounds__(256) void h0_kernel(
    const float* __restrict__ em, const float* __restrict__ W_h0, const float* __restrict__ b_h0,
    float* __restrict__ hbuf, float* __restrict__ cbuf, unsigned short* __restrict__ xbuf) {
  int o = blockIdx.x * 4 + (threadIdx.x >> 6);
  int l = threadIdx.x & 63;
  int b = o >> 10, j = o & 1023;
  const float* wr = &W_h0[(size_t)j * 1024];
  const float* ev = &em[(size_t)b * 1024];
  float v = 0.f;
  #pragma unroll
  for (int i = 0; i < 16; ++i) v += wr[l + i * 64] * ev[l + i * 64];
  #pragma unroll
  for (int off = 32; off; off >>= 1) v += __shfl_down(v, off);
  if (l == 0) {
    v += b_h0[j];
    hbuf[b * 1024 + j] = v;
    cbuf[b * 1024 + j] = v;
    xbuf[b * 2048 + 1024 + j] = f2bf(v);
  }
}

// ---------------- words_bf[m = t*32+b][512] = bf16(dec_emb[target[b][t]])
__global__ void build_words(const int* __restrict__ ts, const float* __restrict__ dec_emb,
                            unsigned short* __restrict__ words_bf) {
  int bi = blockIdx.x;                 // = b*64 + t
  int b = bi >> 6, t = bi & 63;
  int tok = ts[bi];
  int m = t * 32 + b;
  int tid = threadIdx.x;
  float2 v = *(const float2*)&dec_emb[(size_t)tok * E_ + tid * 2];
  words_bf[(size_t)m * E_ + tid * 2]     = f2bf(v.x);
  words_bf[(size_t)m * E_ + tid * 2 + 1] = f2bf(v.y);
}

// ---------------- Wstep[r][0:1024]=W_ih[r][512:1536], [1024:2048]=W_hh[r][:]  (bf16)
__global__ void cast_wstep(const float* __restrict__ W_ih, const float* __restrict__ W_hh,
                           unsigned short* __restrict__ Wstep) {
  int r = blockIdx.x, c = threadIdx.x * 4;
  float4 a = *(const float4*)&W_ih[(size_t)r * 1536 + 512 + c];
  float4 h = *(const float4*)&W_hh[(size_t)r * 1024 + c];
  us4 va; va[0] = f2bf(a.x); va[1] = f2bf(a.y); va[2] = f2bf(a.z); va[3] = f2bf(a.w);
  us4 vh; vh[0] = f2bf(h.x); vh[1] = f2bf(h.y); vh[2] = f2bf(h.z); vh[3] = f2bf(h.w);
  *(us4*)&Wstep[(size_t)r * 2048 + c]        = va;
  *(us4*)&Wstep[(size_t)r * 2048 + 1024 + c] = vh;
}

// ---------------- W_out f32 -> bf16 (optional, ws-size permitting)
__global__ void cast_wout(const float* __restrict__ W, unsigned short* __restrict__ Wb) {
  size_t i = ((size_t)blockIdx.x * 256 + threadIdx.x) * 4;
  float4 f = *(const float4*)&W[i];
  us4 v; v[0] = f2bf(f.x); v[1] = f2bf(f.y); v[2] = f2bf(f.z); v[3] = f2bf(f.w);
  *(us4*)&Wb[i] = v;
}

// ---------------- MFMA GEMM: C[M][N] = A[M][K](bf16) @ B[N][K]^T + biases
// tile 128x128, BK=64, 4 waves (2x2). A via global_load_lds (pre-swizzled source),
// B via glds if bfmt==1 (bf16) else f32->bf16 reg staging. XOR-swizzled LDS
// (k ^ ((row&7)<<3), bijective within 64-short rows) -> conflict-free ds_read_b128.
// XCD-chunked block remap (y-fastest within XCD) so each B-panel is fetched by one XCD.
// mode 0: C[m*ldc + n]   mode 1: C[((m&31)*64 + (m>>5))*ldc + n]
__global__ __launch_bounds__(256) void gemm_bb(
    const unsigned short* __restrict__ A, int lda,
    const void* __restrict__ Bv, int ldb, int bfmt,
    float* __restrict__ C, int ldc,
    const float* __restrict__ bias1, const float* __restrict__ bias2,
    int K, int mode) {
  __shared__ unsigned short sA[128 * 64];
  __shared__ unsigned short sB[128 * 64];
  const int tid = threadIdx.x;
  const int nwg  = gridDim.x * gridDim.y;     // must be % 8 == 0 (4000, 512 ok)
  const int flat = blockIdx.y * gridDim.x + blockIdx.x;
  const int u    = (flat & 7) * (nwg >> 3) + (flat >> 3);
  const int by   = u % gridDim.y;
  const int bx   = u / gridDim.y;
  const int n0 = bx * 128, m0 = by * 128;
  const int w = tid >> 6, l = tid & 63;
  const int wm = w >> 1, wn = w & 1;
  const int l15 = l & 15, q = l >> 4;
  const int xs = (l15 & 7) << 3;
  const int gr = l >> 3;               // glds: row within inst (8 rows x 64B per inst)
  const int gk = (l & 7) << 3;         // glds: short offset within row

  floatx4 acc[4][4];
  #pragma unroll
  for (int i = 0; i < 4; ++i)
    #pragma unroll
    for (int j = 0; j < 4; ++j) acc[i][j] = (floatx4){0.f, 0.f, 0.f, 0.f};

  for (int k0 = 0; k0 < K; k0 += 64) {
    __syncthreads();
    #pragma unroll
    for (int p = 0; p < 4; ++p) {
      int inst = w * 4 + p;
      int row = inst * 8 + gr;
      int kk = gk ^ ((row & 7) << 3);       // inverse-swizzled global source
      glds16(&A[(size_t)(m0 + row) * lda + k0 + kk], &sA[inst * 512]);
    }
    if (bfmt) {
      const unsigned short* Bw = (const unsigned short*)Bv;
      #pragma unroll
      for (int p = 0; p < 4; ++p) {
        int inst = w * 4 + p;
        int row = inst * 8 + gr;
        int kk = gk ^ ((row & 7) << 3);
        glds16(&Bw[(size_t)(n0 + row) * ldb + k0 + kk], &sB[inst * 512]);
      }
    } else {
      const float* Bw = (const float*)Bv;
      #pragma unroll
      for (int p = 0; p < 8; ++p) {
        int idx4 = p * 256 + tid;
        int row = idx4 >> 4, kc = (idx4 & 15) << 2;
        float4 f = *(const float4*)&Bw[(size_t)(n0 + row) * ldb + k0 + kc];
        us4 v; v[0] = f2bf(f.x); v[1] = f2bf(f.y); v[2] = f2bf(f.z); v[3] = f2bf(f.w);
        *(us4*)&sB[row * 64 + (kc ^ ((row & 7) << 3))] = v;
      }
    }
    __syncthreads();
    #pragma unroll
    for (int kk2 = 0; kk2 < 2; ++kk2) {
      const int kr = (kk2 * 32 + q * 8) ^ xs;
      short8 af[4], bf8[4];
      #pragma unroll
      for (int mt = 0; mt < 4; ++mt)
        af[mt] = *(short8*)&sA[(wm * 64 + mt * 16 + l15) * 64 + kr];
      #pragma unroll
      for (int nt = 0; nt < 4; ++nt)
        bf8[nt] = *(short8*)&sB[(wn * 64 + nt * 16 + l15) * 64 + kr];
      #pragma unroll
      for (int mt = 0; mt < 4; ++mt)
        #pragma unroll
        for (int nt = 0; nt < 4; ++nt)
          acc[mt][nt] = __builtin_amdgcn_mfma_f32_16x16x32_bf16(af[mt], bf8[nt], acc[mt][nt], 0, 0, 0);
    }
  }

  #pragma unroll
  for (int mt = 0; mt < 4; ++mt)
    #pragma unroll
    for (int nt = 0; nt < 4; ++nt)
      #pragma unroll
      for (int r = 0; r < 4; ++r) {
        int m = m0 + wm * 64 + mt * 16 + q * 4 + r;
        int n = n0 + wn * 64 + nt * 16 + l15;
        float v = acc[mt][nt][r];
        if (bias1) v += bias1[n];
        if (bias2) v += bias2[n];
        if (mode == 0) {
          C[(size_t)m * ldc + n] = v;
        } else {
          int b = m & 31, t = m >> 5;
          C[(size_t)(b * 64 + t) * ldc + n] = v;
        }
      }
}

// ---------------- persistent recurrence: 64 x { attn (blocks<32) ; bar ; gates ; bar }
// block i owns units u0 = i*4 .. +3 -> its 16 Wstep gate-rows live in LDS for all steps.
// xb0/xb1 ping-pong fixes the h-write/h-read race the 2-kernel version tolerated.
__global__ __launch_bounds__(256, 1) void recurrence(
    const float* __restrict__ enc, float* __restrict__ hbuf, float* __restrict__ cbuf,
    unsigned short* __restrict__ xb0, unsigned short* __restrict__ xb1,
    const unsigned short* __restrict__ Wstep, const float* __restrict__ gw,
    unsigned short* __restrict__ hs, const int* __restrict__ slen,
    unsigned int* __restrict__ bar) {
  __shared__ unsigned short wlds[16 * 2048];   // 64 KB: this block's 16 gate rows (swizzled)
  __shared__ float red[2048];                  // gates reduction; aliased as hsh/esh/ash in attn

  const int tid = threadIdx.x;
  const int w = tid >> 6, l = tid & 63;
  const int l15 = l & 15, q = l >> 4;
  const int u0 = blockIdx.x * 4;

  // one-time: stage Wstep rows into LDS with XOR swizzle (k ^ ((n&7)<<3))
  #pragma unroll
  for (int ii = 0; ii < 16; ++ii) {
    int idx = ii * 256 + tid;
    int n = idx >> 8;
    int kc = (idx & 255) << 3;
    int rn = (n >> 2) * 1024 + u0 + (n & 3);
    short8 v = *(const short8*)&Wstep[(size_t)rn * 2048 + kc];
    *(short8*)&wlds[n * 2048 + (kc ^ ((n & 7) << 3))] = v;
  }

  const int lenb = (blockIdx.x < 32) ? slen[blockIdx.x] : 0;
  float* hsh  = red;          // [1024]
  float* esh  = red + 1024;   // [64]
  float* ashp = red + 1088;   // [64]

  unsigned int bt = 0;

  for (int t = 0; t < 64; ++t) {
    unsigned short* xc = (t & 1) ? xb1 : xb0;   // read (h from prev step, ctx this step)
    unsigned short* xn = (t & 1) ? xb0 : xb1;   // h written here for next step

    // ---- attention (verbatim attn_ctx math), blocks 0..31 only
    if (blockIdx.x < 32) {
      int b = blockIdx.x;
      *(float4*)&hsh[tid * 4] = *(const float4*)&hbuf[(size_t)b * 1024 + tid * 4];
      __syncthreads();
      for (int si = 0; si < 16; ++si) {
        int s = w * 16 + si;
        const float* er = &enc[((size_t)b * S_ + s) * 1024];
        float v = 0.f;
        #pragma unroll
        for (int i = 0; i < 16; ++i) v += er[l + i * 64] * hsh[l + i * 64];
        #pragma unroll
        for (int off = 32; off; off >>= 1) v += __shfl_down(v, off);
        if (l == 0) esh[s] = v;
      }
      __syncthreads();
      if (tid < 64) {
        float e = (tid < lenb) ? esh[tid] : -1e30f;
        float m = e;
        #pragma unroll
        for (int off = 32; off; off >>= 1) m = fmaxf(m, __shfl_down(m, off));
        m = __shfl(m, 0);
        float p = (tid < lenb) ? __expf(e - m) : 0.f;
        float s = p;
        #pragma unroll
        for (int off = 32; off; off >>= 1) s += __shfl_down(s, off);
        s = __shfl(s, 0);
        ashp[tid] = p / s;
      }
      __syncthreads();
      float4 acc = {0, 0, 0, 0};
      const float* eb = &enc[(size_t)b * S_ * 1024 + tid * 4];
      for (int s = 0; s < S_; ++s) {
        float a = ashp[s];
        float4 ev = *(const float4*)&eb[(size_t)s * 1024];
        acc.x += a * ev.x; acc.y += a * ev.y; acc.z += a * ev.z; acc.w += a * ev.w;
      }
      us4 v; v[0] = f2bf(acc.x); v[1] = f2bf(acc.y); v[2] = f2bf(acc.z); v[3] = f2bf(acc.w);
      *(us4*)&xc[b * 2048 + tid * 4] = v;
    }
    bt += 256; gridbar(bar, bt);

    // ---- gates + LSTM update (verbatim step_gates math; B from LDS)
    {
      floatx4 acc0 = (floatx4){0.f, 0.f, 0.f, 0.f};
      floatx4 acc1 = (floatx4){0.f, 0.f, 0.f, 0.f};
      const int kbase = w * 512;
      #pragma unroll 4
      for (int ks = 0; ks < 16; ++ks) {
        int k0 = kbase + ks * 32 + q * 8;
        short8 b8 = *(short8*)&wlds[l15 * 2048 + (k0 ^ ((l15 & 7) << 3))];
        short8 a0 = *(const short8*)&xc[(size_t)l15 * 2048 + k0];
        short8 a1 = *(const short8*)&xc[(size_t)(16 + l15) * 2048 + k0];
        acc0 = __builtin_amdgcn_mfma_f32_16x16x32_bf16(a0, b8, acc0, 0, 0, 0);
        acc1 = __builtin_amdgcn_mfma_f32_16x16x32_bf16(a1, b8, acc1, 0, 0, 0);
      }
      #pragma unroll
      for (int r = 0; r < 4; ++r) {
        red[w * 512 + (q * 4 + r) * 16 + l15]      = acc0[r];
        red[w * 512 + (16 + q * 4 + r) * 16 + l15] = acc1[r];
      }
      __syncthreads();
      if (tid < 128) {
        int b = tid >> 2, ui = tid & 3;
        float g4[4];
        #pragma unroll
        for (int g = 0; g < 4; ++g) {
          int n = g * 4 + ui;
          float s = red[b * 16 + n] + red[512 + b * 16 + n] +
                    red[1024 + b * 16 + n] + red[1536 + b * 16 + n];
          s += gw[(size_t)(t * 32 + b) * 4096 + g * 1024 + u0 + ui];
          g4[g] = s;
        }
        int u = u0 + ui;
        float c_old = cbuf[b * 1024 + u];
        float fi = sigf(g4[0]);
        float ff = sigf(g4[1]);
        float gg = tanhf(g4[2]);
        float fo = sigf(g4[3]);
        float cn = ff * c_old + fi * gg;
        float hn = fo * tanhf(cn);
        cbuf[b * 1024 + u] = cn;
        hbuf[b * 1024 + u] = hn;
        unsigned short hb = f2bf(hn);
        xn[b * 2048 + 1024 + u] = hb;
        hs[(size_t)(t * 32 + b) * 1024 + u] = hb;
      }
    }
    bt += 256; gridbar(bar, bt);
  }
}

extern "C" void kernel_launch(void* const* d_in, const int* in_sizes, int n_in,
                              void* d_out, int out_size, void* d_ws, size_t ws_size,
                              hipStream_t stream) {
  const int*   ts     = (const int*)d_in[0];    // target_sentences [B,T]
  const int*   slen   = (const int*)d_in[2];    // source_lengths [B]
  const int*   ss     = (const int*)d_in[3];    // source_sentences [B,S]
  const int*   pp     = (const int*)d_in[4];    // positions [B,S]
  const float* enc_emb = (const float*)d_in[8];
  const float* pos_emb = (const float*)d_in[9];
  const float* dec_emb = (const float*)d_in[10];
  const float* W_h0   = (const float*)d_in[11];
  const float* b_h0   = (const float*)d_in[12];
  const float* W_ih   = (const float*)d_in[13];
  const float* W_hh   = (const float*)d_in[14];
  const float* b_ih   = (const float*)d_in[15];
  const float* b_hh   = (const float*)d_in[16];
  const float* W_out  = (const float*)d_in[17];
  const float* b_out  = (const float*)d_in[18];
  float* out = (float*)d_out;

  // workspace carve-up
  char* base = (char*)d_ws;
  size_t off = 0;
  auto carve = [&](size_t bytes) { void* p = base + off; off += (bytes + 255) & ~(size_t)255; return p; };
  float*          enc      = (float*)carve((size_t)B_ * S_ * 1024 * 4);      // 8.39 MB
  float*          em       = (float*)carve((size_t)B_ * 1024 * 4);
  float*          hbuf     = (float*)carve((size_t)B_ * 1024 * 4);
  float*          cbuf     = (float*)carve((size_t)B_ * 1024 * 4);
  unsigned short* xb0      = (unsigned short*)carve((size_t)B_ * 2048 * 2);
  unsigned short* xb1      = (unsigned short*)carve((size_t)B_ * 2048 * 2);
  unsigned short* words_bf = (unsigned short*)carve((size_t)2048 * E_ * 2);  // 2.10 MB
  unsigned short* Wstep    = (unsigned short*)carve((size_t)4096 * 2048 * 2);// 16.8 MB
  float*          gw       = (float*)carve((size_t)2048 * 4096 * 4);         // 33.6 MB
  unsigned short* hs       = (unsigned short*)carve((size_t)2048 * 1024 * 2);// 4.19 MB
  unsigned int*   bar      = (unsigned int*)carve(256);
  unsigned short* Wob      = (unsigned short*)carve((size_t)VT_ * 1024 * 2); // 65.5 MB (optional)
  const bool haveWob = (off <= ws_size);

  hipMemsetAsync(bar, 0, sizeof(unsigned int), stream);

  // ---- prep (order enforced by stream)
  build_enc  <<<B_ * S_, 256, 0, stream>>>(ss, pp, enc_emb, pos_emb, enc);
  enc_mean   <<<B_,      256, 0, stream>>>(enc, em);
  h0_kernel  <<<(B_ * H_) / 4, 256, 0, stream>>>(em, W_h0, b_h0, hbuf, cbuf, xb0);
  build_words<<<B_ * T_, 256, 0, stream>>>(ts, dec_emb, words_bf);
  cast_wstep <<<4096,    256, 0, stream>>>(W_ih, W_hh, Wstep);
  if (haveWob) cast_wout<<<VT_, 256, 0, stream>>>(W_out, Wob);

  // gw = words @ W_ih[:, :512]^T + b_ih + b_hh    (M=2048, N=4096, K=512; B = f32 W_ih)
  gemm_bb<<<dim3(4096 / 128, 2048 / 128), 256, 0, stream>>>(
      words_bf, E_, (const void*)W_ih, 1536, 0, gw, 4096, b_ih, b_hh, E_, 0);

  // ---- full recurrence in one persistent kernel (64 steps, 2 grid barriers/step)
  recurrence<<<256, 256, 0, stream>>>(enc, hbuf, cbuf, xb0, xb1, Wstep, gw, hs, slen, bar);

  // ---- out = hs @ W_out^T + b_out  (M=2048, N=32000, K=1024), remapped to [B,T,V]
  gemm_bb<<<dim3(VT_ / 128, 2048 / 128), 256, 0, stream>>>(
      hs, H_, haveWob ? (const void*)Wob : (const void*)W_out, H_, haveWob ? 1 : 0,
      out, VT_, b_out, nullptr, H_, 1);
}

// Round 2
// 2284.576 us; speedup vs baseline: 1.7600x; 1.7600x over previous
//
#include <hip/hip_runtime.h>
#include <cstdint>
#include <cstddef>

// Problem constants (fixed by harness)
#define B_  32
#define S_  64
#define T_  64
#define E_  512
#define H_  1024   // = 2E
#define VT_ 32000

#define AGENT __HIP_MEMORY_SCOPE_AGENT

using short8  = __attribute__((ext_vector_type(8))) short;
using floatx4 = __attribute__((ext_vector_type(4))) float;
using us4     = __attribute__((ext_vector_type(4))) unsigned short;
using u64x2   = __attribute__((ext_vector_type(2))) unsigned long long;

__device__ __forceinline__ unsigned short f2bf(float f) {
  unsigned int u = __builtin_bit_cast(unsigned int, f);
  u = u + 0x7fffu + ((u >> 16) & 1u);     // RNE
  return (unsigned short)(u >> 16);
}
__device__ __forceinline__ float sigf(float x) { return 1.f / (1.f + __expf(-x)); }

// ---- coherence-point (Infinity Cache) data path: agent-scope relaxed atomics
// emit sc0 sc1 (bypass L1+L2) -> cross-XCD visible without any cache flush.
__device__ __forceinline__ short8 aload16(const unsigned short* p) {
  u64x2 v;
  v[0] = __hip_atomic_load((unsigned long long*)p,       __ATOMIC_RELAXED, AGENT);
  v[1] = __hip_atomic_load((unsigned long long*)(p + 4), __ATOMIC_RELAXED, AGENT);
  return __builtin_bit_cast(short8, v);
}
__device__ __forceinline__ float4 aload16f(const float* p) {
  u64x2 v;
  v[0] = __hip_atomic_load((unsigned long long*)p,       __ATOMIC_RELAXED, AGENT);
  v[1] = __hip_atomic_load((unsigned long long*)(p + 2), __ATOMIC_RELAXED, AGENT);
  return __builtin_bit_cast(float4, v);
}
__device__ __forceinline__ void astore8(unsigned short* p, us4 v) {
  __hip_atomic_store((unsigned long long*)p, __builtin_bit_cast(unsigned long long, v),
                     __ATOMIC_RELAXED, AGENT);
}
__device__ __forceinline__ void astoref(float* p, float v) {
  __hip_atomic_store((unsigned int*)p, __builtin_bit_cast(unsigned int, v),
                     __ATOMIC_RELAXED, AGENT);
}

// async global->LDS, 16B per lane; LDS dest is wave-uniform base + lane*16
__device__ __forceinline__ void glds16(const void* g, void* l) {
  __builtin_amdgcn_global_load_lds(
      (const __attribute__((address_space(1))) unsigned int*)g,
      (__attribute__((address_space(3))) unsigned int*)l, 16, 0, 0);
}

// ---- fence-free tree grid barrier (monotonic counters, no reset).
// layout (uints): [g*16] 8 group counters (64B apart), [128] root, [144] release.
// __syncthreads' implicit vmcnt(0) drains each wave's sc0sc1 stores to the
// coherence point before thread 0 signals arrival -> no buffer_wbl2/buffer_inv.
__device__ __forceinline__ void gridbar(unsigned int* bar, unsigned int step) {
  asm volatile("s_waitcnt vmcnt(0)" ::: "memory");
  __syncthreads();
  if (threadIdx.x == 0) {
    const unsigned g = blockIdx.x & 7u;
    unsigned prev = __hip_atomic_fetch_add(&bar[g * 16], 1u, __ATOMIC_RELAXED, AGENT);
    if ((prev & 31u) == 31u) {                 // last of this group's 32 arrivals
      unsigned rp = __hip_atomic_fetch_add(&bar[128], 1u, __ATOMIC_RELAXED, AGENT);
      if ((rp & 7u) == 7u)                     // last of 8 groups -> release
        __hip_atomic_store(&bar[144], (rp >> 3) + 1u, __ATOMIC_RELAXED, AGENT);
    }
    while (__hip_atomic_load(&bar[144], __ATOMIC_RELAXED, AGENT) < step + 1u)
      __builtin_amdgcn_s_sleep(4);
    asm volatile("" ::: "memory");
  }
  __syncthreads();
}

// ---------------- enc = concat(enc_emb[src], pos_emb[pos])  [B*S][1024] f32
__global__ void build_enc(const int* __restrict__ ss, const int* __restrict__ pp,
                          const float* __restrict__ enc_emb, const float* __restrict__ pos_emb,
                          float* __restrict__ enc) {
  int row = blockIdx.x, tid = threadIdx.x;
  int tok = ss[row], pos = pp[row];
  float2 a = *(const float2*)&enc_emb[(size_t)tok * E_ + tid * 2];
  float2 p = *(const float2*)&pos_emb[(size_t)pos * E_ + tid * 2];
  *(float2*)&enc[(size_t)row * 1024 + tid * 2]       = a;
  *(float2*)&enc[(size_t)row * 1024 + 512 + tid * 2] = p;
}

// ---------------- encmean[b][d] = mean over s
__global__ void enc_mean(const float* __restrict__ enc, float* __restrict__ em) {
  int b = blockIdx.x, tid = threadIdx.x;
  float4 acc = {0, 0, 0, 0};
  for (int s = 0; s < S_; ++s) {
    float4 v = *(const float4*)&enc[((size_t)b * S_ + s) * 1024 + tid * 4];
    acc.x += v.x; acc.y += v.y; acc.z += v.z; acc.w += v.w;
  }
  const float inv = 1.f / 64.f;
  acc.x *= inv; acc.y *= inv; acc.z *= inv; acc.w *= inv;
  *(float4*)&em[(size_t)b * 1024 + tid * 4] = acc;
}

// ---------------- h0 = encmean @ W_h0^T + b_h0 ; c0 = h0 (wave-per-output dot)
__global__ __launch_bounds__(256) void h0_kernel(
    const float* __restrict__ em, const float* __restrict__ W_h0, const float* __restrict__ b_h0,
    float* __restrict__ hbuf, float* __restrict__ cbuf, unsigned short* __restrict__ xbuf) {
  int o = blockIdx.x * 4 + (threadIdx.x >> 6);
  int l = threadIdx.x & 63;
  int b = o >> 10, j = o & 1023;
  const float* wr = &W_h0[(size_t)j * 1024];
  const float* ev = &em[(size_t)b * 1024];
  float v = 0.f;
  #pragma unroll
  for (int i = 0; i < 16; ++i) v += wr[l + i * 64] * ev[l + i * 64];
  #pragma unroll
  for (int off = 32; off; off >>= 1) v += __shfl_down(v, off);
  if (l == 0) {
    v += b_h0[j];
    hbuf[b * 1024 + j] = v;
    cbuf[b * 1024 + j] = v;
    xbuf[b * 2048 + 1024 + j] = f2bf(v);
  }
}

// ---------------- words_bf[m = t*32+b][512] = bf16(dec_emb[target[b][t]])
__global__ void build_words(const int* __restrict__ ts, const float* __restrict__ dec_emb,
                            unsigned short* __restrict__ words_bf) {
  int bi = blockIdx.x;                 // = b*64 + t
  int b = bi >> 6, t = bi & 63;
  int tok = ts[bi];
  int m = t * 32 + b;
  int tid = threadIdx.x;
  float2 v = *(const float2*)&dec_emb[(size_t)tok * E_ + tid * 2];
  words_bf[(size_t)m * E_ + tid * 2]     = f2bf(v.x);
  words_bf[(size_t)m * E_ + tid * 2 + 1] = f2bf(v.y);
}

// ---------------- Wstep[r][0:1024]=W_ih[r][512:1536], [1024:2048]=W_hh[r][:]  (bf16)
__global__ void cast_wstep(const float* __restrict__ W_ih, const float* __restrict__ W_hh,
                           unsigned short* __restrict__ Wstep) {
  int r = blockIdx.x, c = threadIdx.x * 4;
  float4 a = *(const float4*)&W_ih[(size_t)r * 1536 + 512 + c];
  float4 h = *(const float4*)&W_hh[(size_t)r * 1024 + c];
  us4 va; va[0] = f2bf(a.x); va[1] = f2bf(a.y); va[2] = f2bf(a.z); va[3] = f2bf(a.w);
  us4 vh; vh[0] = f2bf(h.x); vh[1] = f2bf(h.y); vh[2] = f2bf(h.z); vh[3] = f2bf(h.w);
  *(us4*)&Wstep[(size_t)r * 2048 + c]        = va;
  *(us4*)&Wstep[(size_t)r * 2048 + 1024 + c] = vh;
}

// ---------------- W_out f32 -> bf16 (optional, ws-size permitting)
__global__ void cast_wout(const float* __restrict__ W, unsigned short* __restrict__ Wb) {
  size_t i = ((size_t)blockIdx.x * 256 + threadIdx.x) * 4;
  float4 f = *(const float4*)&W[i];
  us4 v; v[0] = f2bf(f.x); v[1] = f2bf(f.y); v[2] = f2bf(f.z); v[3] = f2bf(f.w);
  *(us4*)&Wb[i] = v;
}

// ---------------- MFMA GEMM: C[M][N] = A[M][K](bf16) @ B[N][K]^T + biases
// tile 128x128, BK=64, 4 waves (2x2). A via global_load_lds (pre-swizzled source),
// B via glds if bfmt==1 (bf16) else f32->bf16 reg staging. XOR-swizzled LDS
// (k ^ ((row&7)<<3)) -> conflict-free ds_read_b128. XCD-chunked block remap.
// mode 0: C[m*ldc + n]   mode 1: C[((m&31)*64 + (m>>5))*ldc + n]
__global__ __launch_bounds__(256) void gemm_bb(
    const unsigned short* __restrict__ A, int lda,
    const void* __restrict__ Bv, int ldb, int bfmt,
    float* __restrict__ C, int ldc,
    const float* __restrict__ bias1, const float* __restrict__ bias2,
    int K, int mode) {
  __shared__ unsigned short sA[128 * 64];
  __shared__ unsigned short sB[128 * 64];
  const int tid = threadIdx.x;
  const int nwg  = gridDim.x * gridDim.y;     // must be % 8 == 0 (4000, 512 ok)
  const int flat = blockIdx.y * gridDim.x + blockIdx.x;
  const int u    = (flat & 7) * (nwg >> 3) + (flat >> 3);
  const int by   = u % gridDim.y;
  const int bx   = u / gridDim.y;
  const int n0 = bx * 128, m0 = by * 128;
  const int w = tid >> 6, l = tid & 63;
  const int wm = w >> 1, wn = w & 1;
  const int l15 = l & 15, q = l >> 4;
  const int xs = (l15 & 7) << 3;
  const int gr = l >> 3;               // glds: row within inst (8 rows x 64B per inst)
  const int gk = (l & 7) << 3;         // glds: short offset within row

  floatx4 acc[4][4];
  #pragma unroll
  for (int i = 0; i < 4; ++i)
    #pragma unroll
    for (int j = 0; j < 4; ++j) acc[i][j] = (floatx4){0.f, 0.f, 0.f, 0.f};

  for (int k0 = 0; k0 < K; k0 += 64) {
    __syncthreads();
    #pragma unroll
    for (int p = 0; p < 4; ++p) {
      int inst = w * 4 + p;
      int row = inst * 8 + gr;
      int kk = gk ^ ((row & 7) << 3);       // inverse-swizzled global source
      glds16(&A[(size_t)(m0 + row) * lda + k0 + kk], &sA[inst * 512]);
    }
    if (bfmt) {
      const unsigned short* Bw = (const unsigned short*)Bv;
      #pragma unroll
      for (int p = 0; p < 4; ++p) {
        int inst = w * 4 + p;
        int row = inst * 8 + gr;
        int kk = gk ^ ((row & 7) << 3);
        glds16(&Bw[(size_t)(n0 + row) * ldb + k0 + kk], &sB[inst * 512]);
      }
    } else {
      const float* Bw = (const float*)Bv;
      #pragma unroll
      for (int p = 0; p < 8; ++p) {
        int idx4 = p * 256 + tid;
        int row = idx4 >> 4, kc = (idx4 & 15) << 2;
        float4 f = *(const float4*)&Bw[(size_t)(n0 + row) * ldb + k0 + kc];
        us4 v; v[0] = f2bf(f.x); v[1] = f2bf(f.y); v[2] = f2bf(f.z); v[3] = f2bf(f.w);
        *(us4*)&sB[row * 64 + (kc ^ ((row & 7) << 3))] = v;
      }
    }
    __syncthreads();
    #pragma unroll
    for (int kk2 = 0; kk2 < 2; ++kk2) {
      const int kr = (kk2 * 32 + q * 8) ^ xs;
      short8 af[4], bf8[4];
      #pragma unroll
      for (int mt = 0; mt < 4; ++mt)
        af[mt] = *(short8*)&sA[(wm * 64 + mt * 16 + l15) * 64 + kr];
      #pragma unroll
      for (int nt = 0; nt < 4; ++nt)
        bf8[nt] = *(short8*)&sB[(wn * 64 + nt * 16 + l15) * 64 + kr];
      #pragma unroll
      for (int mt = 0; mt < 4; ++mt)
        #pragma unroll
        for (int nt = 0; nt < 4; ++nt)
          acc[mt][nt] = __builtin_amdgcn_mfma_f32_16x16x32_bf16(af[mt], bf8[nt], acc[mt][nt], 0, 0, 0);
    }
  }

  #pragma unroll
  for (int mt = 0; mt < 4; ++mt)
    #pragma unroll
    for (int nt = 0; nt < 4; ++nt)
      #pragma unroll
      for (int r = 0; r < 4; ++r) {
        int m = m0 + wm * 64 + mt * 16 + q * 4 + r;
        int n = n0 + wn * 64 + nt * 16 + l15;
        float v = acc[mt][nt][r];
        if (bias1) v += bias1[n];
        if (bias2) v += bias2[n];
        if (mode == 0) {
          C[(size_t)m * ldc + n] = v;
        } else {
          int b = m & 31, t = m >> 5;
          C[(size_t)(b * 64 + t) * ldc + n] = v;
        }
      }
}

// ---------------- persistent recurrence: 64 x { attn (blocks<32) ; bar ; gates ; bar }
// Shared mutable data (xb0/xb1, hbuf) goes through the IF$ coherence point via
// agent-scope relaxed atomics; read-only data (enc, gw, Wstep) stays L2-cached
// (no invalidates anywhere). Block i owns units u0=i*4..+3 (16 Wstep rows in LDS).
__global__ __launch_bounds__(256, 1) void recurrence(
    const float* __restrict__ enc, float* __restrict__ hbuf, float* __restrict__ cbuf,
    unsigned short* __restrict__ xb0, unsigned short* __restrict__ xb1,
    const unsigned short* __restrict__ Wstep, const float* __restrict__ gw,
    unsigned short* __restrict__ hs, const int* __restrict__ slen,
    unsigned int* __restrict__ bar) {
  __shared__ unsigned short wlds[16 * 2048];   // 64 KB: this block's 16 gate rows (swizzled)
  __shared__ float red[2048];                  // gates reduction; aliased as hsh/esh/ash in attn

  const int tid = threadIdx.x;
  const int w = tid >> 6, l = tid & 63;
  const int l15 = l & 15, q = l >> 4;
  const int u0 = blockIdx.x * 4;

  // one-time: stage Wstep rows into LDS with XOR swizzle (k ^ ((n&7)<<3))
  #pragma unroll
  for (int ii = 0; ii < 16; ++ii) {
    int idx = ii * 256 + tid;
    int n = idx >> 8;
    int kc = (idx & 255) << 3;
    int rn = (n >> 2) * 1024 + u0 + (n & 3);
    short8 v = *(const short8*)&Wstep[(size_t)rn * 2048 + kc];
    *(short8*)&wlds[n * 2048 + (kc ^ ((n & 7) << 3))] = v;
  }

  const int lenb = (blockIdx.x < 32) ? slen[blockIdx.x] : 0;
  float* hsh  = red;          // [1024]
  float* esh  = red + 1024;   // [64]
  float* ashp = red + 1088;   // [64]

  unsigned int bt = 0;

  for (int t = 0; t < 64; ++t) {
    unsigned short* xc = (t & 1) ? xb1 : xb0;   // read (h from prev step, ctx this step)
    unsigned short* xn = (t & 1) ? xb0 : xb1;   // h written here for next step

    // ---- attention (blocks 0..31 only); hbuf via coherent loads
    if (blockIdx.x < 32) {
      int b = blockIdx.x;
      *(float4*)&hsh[tid * 4] = aload16f(&hbuf[(size_t)b * 1024 + tid * 4]);
      __syncthreads();
      for (int si = 0; si < 16; ++si) {
        int s = w * 16 + si;
        const float* er = &enc[((size_t)b * S_ + s) * 1024];
        float v = 0.f;
        #pragma unroll
        for (int i = 0; i < 16; ++i) v += er[l + i * 64] * hsh[l + i * 64];
        #pragma unroll
        for (int off = 32; off; off >>= 1) v += __shfl_down(v, off);
        if (l == 0) esh[s] = v;
      }
      __syncthreads();
      if (tid < 64) {
        float e = (tid < lenb) ? esh[tid] : -1e30f;
        float m = e;
        #pragma unroll
        for (int off = 32; off; off >>= 1) m = fmaxf(m, __shfl_down(m, off));
        m = __shfl(m, 0);
        float p = (tid < lenb) ? __expf(e - m) : 0.f;
        float s = p;
        #pragma unroll
        for (int off = 32; off; off >>= 1) s += __shfl_down(s, off);
        s = __shfl(s, 0);
        ashp[tid] = p / s;
      }
      __syncthreads();
      float4 acc = {0, 0, 0, 0};
      const float* eb = &enc[(size_t)b * S_ * 1024 + tid * 4];
      for (int s = 0; s < S_; ++s) {
        float a = ashp[s];
        float4 ev = *(const float4*)&eb[(size_t)s * 1024];
        acc.x += a * ev.x; acc.y += a * ev.y; acc.z += a * ev.z; acc.w += a * ev.w;
      }
      us4 v; v[0] = f2bf(acc.x); v[1] = f2bf(acc.y); v[2] = f2bf(acc.z); v[3] = f2bf(acc.w);
      astore8(&xc[b * 2048 + tid * 4], v);
    }
    gridbar(bar, bt); ++bt;

    // ---- gates + LSTM update (x via coherent loads, W from LDS)
    {
      floatx4 acc0 = (floatx4){0.f, 0.f, 0.f, 0.f};
      floatx4 acc1 = (floatx4){0.f, 0.f, 0.f, 0.f};
      const int kbase = w * 512;
      #pragma unroll 8
      for (int ks = 0; ks < 16; ++ks) {
        int k0 = kbase + ks * 32 + q * 8;
        short8 b8 = *(short8*)&wlds[l15 * 2048 + (k0 ^ ((l15 & 7) << 3))];
        short8 a0 = aload16(&xc[(size_t)l15 * 2048 + k0]);
        short8 a1 = aload16(&xc[(size_t)(16 + l15) * 2048 + k0]);
        acc0 = __builtin_amdgcn_mfma_f32_16x16x32_bf16(a0, b8, acc0, 0, 0, 0);
        acc1 = __builtin_amdgcn_mfma_f32_16x16x32_bf16(a1, b8, acc1, 0, 0, 0);
      }
      #pragma unroll
      for (int r = 0; r < 4; ++r) {
        red[w * 512 + (q * 4 + r) * 16 + l15]      = acc0[r];
        red[w * 512 + (16 + q * 4 + r) * 16 + l15] = acc1[r];
      }
      __syncthreads();
      if (tid < 128) {
        int b = tid >> 2, ui = tid & 3;
        float g4[4];
        #pragma unroll
        for (int g = 0; g < 4; ++g) {
          int n = g * 4 + ui;
          float s = red[b * 16 + n] + red[512 + b * 16 + n] +
                    red[1024 + b * 16 + n] + red[1536 + b * 16 + n];
          s += gw[(size_t)(t * 32 + b) * 4096 + g * 1024 + u0 + ui];
          g4[g] = s;
        }
        int u = u0 + ui;
        float c_old = cbuf[b * 1024 + u];
        float fi = sigf(g4[0]);
        float ff = sigf(g4[1]);
        float gg = tanhf(g4[2]);
        float fo = sigf(g4[3]);
        float cn = ff * c_old + fi * gg;
        float hn = fo * tanhf(cn);
        cbuf[b * 1024 + u] = cn;                 // block-private: normal cached
        astoref(&hbuf[b * 1024 + u], hn);        // cross-block: coherent
        unsigned short hb = f2bf(hn);
        hs[(size_t)(t * 32 + b) * 1024 + u] = hb;// read only by next kernel launch
        // pack this b's 4 units (lanes 4b..4b+3 of the wave) into one 8B store
        unsigned hv = (unsigned)hb;
        unsigned p0 = __shfl(hv, (l & ~3) + 0);
        unsigned p1 = __shfl(hv, (l & ~3) + 1);
        unsigned p2 = __shfl(hv, (l & ~3) + 2);
        unsigned p3 = __shfl(hv, (l & ~3) + 3);
        if (ui == 0) {
          unsigned long long pk = (unsigned long long)p0 |
                                  ((unsigned long long)p1 << 16) |
                                  ((unsigned long long)p2 << 32) |
                                  ((unsigned long long)p3 << 48);
          __hip_atomic_store((unsigned long long*)&xn[b * 2048 + 1024 + u0], pk,
                             __ATOMIC_RELAXED, AGENT);
        }
      }
    }
    gridbar(bar, bt); ++bt;
  }
}

extern "C" void kernel_launch(void* const* d_in, const int* in_sizes, int n_in,
                              void* d_out, int out_size, void* d_ws, size_t ws_size,
                              hipStream_t stream) {
  const int*   ts     = (const int*)d_in[0];    // target_sentences [B,T]
  const int*   slen   = (const int*)d_in[2];    // source_lengths [B]
  const int*   ss     = (const int*)d_in[3];    // source_sentences [B,S]
  const int*   pp     = (const int*)d_in[4];    // positions [B,S]
  const float* enc_emb = (const float*)d_in[8];
  const float* pos_emb = (const float*)d_in[9];
  const float* dec_emb = (const float*)d_in[10];
  const float* W_h0   = (const float*)d_in[11];
  const float* b_h0   = (const float*)d_in[12];
  const float* W_ih   = (const float*)d_in[13];
  const float* W_hh   = (const float*)d_in[14];
  const float* b_ih   = (const float*)d_in[15];
  const float* b_hh   = (const float*)d_in[16];
  const float* W_out  = (const float*)d_in[17];
  const float* b_out  = (const float*)d_in[18];
  float* out = (float*)d_out;

  // workspace carve-up
  char* base = (char*)d_ws;
  size_t off = 0;
  auto carve = [&](size_t bytes) { void* p = base + off; off += (bytes + 255) & ~(size_t)255; return p; };
  float*          enc      = (float*)carve((size_t)B_ * S_ * 1024 * 4);      // 8.39 MB
  float*          em       = (float*)carve((size_t)B_ * 1024 * 4);
  float*          hbuf     = (float*)carve((size_t)B_ * 1024 * 4);
  float*          cbuf     = (float*)carve((size_t)B_ * 1024 * 4);
  unsigned short* xb0      = (unsigned short*)carve((size_t)B_ * 2048 * 2);
  unsigned short* xb1      = (unsigned short*)carve((size_t)B_ * 2048 * 2);
  unsigned short* words_bf = (unsigned short*)carve((size_t)2048 * E_ * 2);  // 2.10 MB
  unsigned short* Wstep    = (unsigned short*)carve((size_t)4096 * 2048 * 2);// 16.8 MB
  float*          gw       = (float*)carve((size_t)2048 * 4096 * 4);         // 33.6 MB
  unsigned short* hs       = (unsigned short*)carve((size_t)2048 * 1024 * 2);// 4.19 MB
  unsigned int*   bar      = (unsigned int*)carve(1024);
  unsigned short* Wob      = (unsigned short*)carve((size_t)VT_ * 1024 * 2); // 65.5 MB (optional)
  const bool haveWob = (off <= ws_size);

  hipMemsetAsync(bar, 0, 1024, stream);

  // ---- prep (order enforced by stream)
  build_enc  <<<B_ * S_, 256, 0, stream>>>(ss, pp, enc_emb, pos_emb, enc);
  enc_mean   <<<B_,      256, 0, stream>>>(enc, em);
  h0_kernel  <<<(B_ * H_) / 4, 256, 0, stream>>>(em, W_h0, b_h0, hbuf, cbuf, xb0);
  build_words<<<B_ * T_, 256, 0, stream>>>(ts, dec_emb, words_bf);
  cast_wstep <<<4096,    256, 0, stream>>>(W_ih, W_hh, Wstep);
  if (haveWob) cast_wout<<<VT_, 256, 0, stream>>>(W_out, Wob);

  // gw = words @ W_ih[:, :512]^T + b_ih + b_hh    (M=2048, N=4096, K=512; B = f32 W_ih)
  gemm_bb<<<dim3(4096 / 128, 2048 / 128), 256, 0, stream>>>(
      words_bf, E_, (const void*)W_ih, 1536, 0, gw, 4096, b_ih, b_hh, E_, 0);

  // ---- full recurrence in one persistent kernel (64 steps, 2 tree barriers/step)
  recurrence<<<256, 256, 0, stream>>>(enc, hbuf, cbuf, xb0, xb1, Wstep, gw, hs, slen, bar);

  // ---- out = hs @ W_out^T + b_out  (M=2048, N=32000, K=1024), remapped to [B,T,V]
  gemm_bb<<<dim3(VT_ / 128, 2048 / 128), 256, 0, stream>>>(
      hs, H_, haveWob ? (const void*)Wob : (const void*)W_out, H_, haveWob ? 1 : 0,
      out, VT_, b_out, nullptr, H_, 1);
}

// Round 3
// 2190.370 us; speedup vs baseline: 1.8357x; 1.0430x over previous
//
#include <hip/hip_runtime.h>
#include <cstdint>
#include <cstddef>

// Problem constants (fixed by harness)
#define B_  32
#define S_  64
#define T_  64
#define E_  512
#define H_  1024   // = 2E
#define VT_ 32000

#define AGENT __HIP_MEMORY_SCOPE_AGENT

using short8  = __attribute__((ext_vector_type(8))) short;
using floatx4 = __attribute__((ext_vector_type(4))) float;
using us4     = __attribute__((ext_vector_type(4))) unsigned short;

__device__ __forceinline__ unsigned short f2bf(float f) {
  unsigned int u = __builtin_bit_cast(unsigned int, f);
  u = u + 0x7fffu + ((u >> 16) & 1u);     // RNE
  return (unsigned short)(u >> 16);
}
__device__ __forceinline__ float bf2f(short s) {
  unsigned int u = ((unsigned int)(unsigned short)s) << 16;
  return __builtin_bit_cast(float, u);
}
__device__ __forceinline__ float sigf(float x) { return 1.f / (1.f + __expf(-x)); }

// sc0sc1 (coherence-point) stores: cross-XCD visible, no cache flush needed.
__device__ __forceinline__ void astore8(unsigned short* p, us4 v) {
  __hip_atomic_store((unsigned long long*)p, __builtin_bit_cast(unsigned long long, v),
                     __ATOMIC_RELAXED, AGENT);
}
__device__ __forceinline__ void astoref(float* p, float v) {
  __hip_atomic_store((unsigned int*)p, __builtin_bit_cast(unsigned int, v),
                     __ATOMIC_RELAXED, AGENT);
}

// async global->LDS, 16B per lane; LDS dest is wave-uniform base + lane*16
__device__ __forceinline__ void glds16(const void* g, void* l) {
  __builtin_amdgcn_global_load_lds(
      (const __attribute__((address_space(1))) unsigned int*)g,
      (__attribute__((address_space(3))) unsigned int*)l, 16, 0, 0);
}

// ---- atomic-free grid barrier: per-block arrival slot (monotonic step value),
// wave 0 of every block polls all 256 slots. No RMW contention, no release chain.
// Requires all 256 blocks co-resident (1 block/CU, launch_bounds(256,1)).
__device__ __forceinline__ void gridbar(unsigned int* slots, unsigned int arrive) {
  asm volatile("s_waitcnt vmcnt(0)" ::: "memory");   // drain sc0sc1 data stores
  __syncthreads();
  if (threadIdx.x < 64) {
    if (threadIdx.x == 0)
      __hip_atomic_store(&slots[blockIdx.x], arrive, __ATOMIC_RELAXED, AGENT);
    const int l = threadIdx.x;
    for (;;) {
      unsigned a0 = __hip_atomic_load(&slots[l],       __ATOMIC_RELAXED, AGENT);
      unsigned a1 = __hip_atomic_load(&slots[l + 64],  __ATOMIC_RELAXED, AGENT);
      unsigned a2 = __hip_atomic_load(&slots[l + 128], __ATOMIC_RELAXED, AGENT);
      unsigned a3 = __hip_atomic_load(&slots[l + 192], __ATOMIC_RELAXED, AGENT);
      if (__all(a0 >= arrive && a1 >= arrive && a2 >= arrive && a3 >= arrive)) break;
      __builtin_amdgcn_s_sleep(1);
    }
  }
  __syncthreads();
}

// ---------------- enc = concat(enc_emb[src], pos_emb[pos])  f32 [B*S][1024] + bf16 copy
__global__ void build_enc(const int* __restrict__ ss, const int* __restrict__ pp,
                          const float* __restrict__ enc_emb, const float* __restrict__ pos_emb,
                          float* __restrict__ enc, unsigned short* __restrict__ enc_bf) {
  int row = blockIdx.x, tid = threadIdx.x;
  int tok = ss[row], pos = pp[row];
  float2 a = *(const float2*)&enc_emb[(size_t)tok * E_ + tid * 2];
  float2 p = *(const float2*)&pos_emb[(size_t)pos * E_ + tid * 2];
  *(float2*)&enc[(size_t)row * 1024 + tid * 2]       = a;
  *(float2*)&enc[(size_t)row * 1024 + 512 + tid * 2] = p;
  unsigned pa = (unsigned)f2bf(a.x) | ((unsigned)f2bf(a.y) << 16);
  unsigned pb = (unsigned)f2bf(p.x) | ((unsigned)f2bf(p.y) << 16);
  *(unsigned*)&enc_bf[(size_t)row * 1024 + tid * 2]       = pa;
  *(unsigned*)&enc_bf[(size_t)row * 1024 + 512 + tid * 2] = pb;
}

// ---------------- encmean[b][d] = mean over s
__global__ void enc_mean(const float* __restrict__ enc, float* __restrict__ em) {
  int b = blockIdx.x, tid = threadIdx.x;
  float4 acc = {0, 0, 0, 0};
  for (int s = 0; s < S_; ++s) {
    float4 v = *(const float4*)&enc[((size_t)b * S_ + s) * 1024 + tid * 4];
    acc.x += v.x; acc.y += v.y; acc.z += v.z; acc.w += v.w;
  }
  const float inv = 1.f / 64.f;
  acc.x *= inv; acc.y *= inv; acc.z *= inv; acc.w *= inv;
  *(float4*)&em[(size_t)b * 1024 + tid * 4] = acc;
}

// ---------------- h0 = encmean @ W_h0^T + b_h0 -> hring[0], cbuf, xring[0] h-half
__global__ __launch_bounds__(256) void h0_kernel(
    const float* __restrict__ em, const float* __restrict__ W_h0, const float* __restrict__ b_h0,
    float* __restrict__ cbuf, float* __restrict__ hr0, unsigned short* __restrict__ xr0) {
  int o = blockIdx.x * 4 + (threadIdx.x >> 6);
  int l = threadIdx.x & 63;
  int b = o >> 10, j = o & 1023;
  const float* wr = &W_h0[(size_t)j * 1024];
  const float* ev = &em[(size_t)b * 1024];
  float v = 0.f;
  #pragma unroll
  for (int i = 0; i < 16; ++i) v += wr[l + i * 64] * ev[l + i * 64];
  #pragma unroll
  for (int off = 32; off; off >>= 1) v += __shfl_down(v, off);
  if (l == 0) {
    v += b_h0[j];
    cbuf[b * 1024 + j] = v;
    hr0[b * 1024 + j] = v;
    xr0[b * 2048 + 1024 + j] = f2bf(v);
  }
}

// ---------------- words_bf[m = t*32+b][512] = bf16(dec_emb[target[b][t]])
__global__ void build_words(const int* __restrict__ ts, const float* __restrict__ dec_emb,
                            unsigned short* __restrict__ words_bf) {
  int bi = blockIdx.x;                 // = b*64 + t
  int b = bi >> 6, t = bi & 63;
  int tok = ts[bi];
  int m = t * 32 + b;
  int tid = threadIdx.x;
  float2 v = *(const float2*)&dec_emb[(size_t)tok * E_ + tid * 2];
  words_bf[(size_t)m * E_ + tid * 2]     = f2bf(v.x);
  words_bf[(size_t)m * E_ + tid * 2 + 1] = f2bf(v.y);
}

// ---------------- Wstep[r][0:1024]=W_ih[r][512:1536], [1024:2048]=W_hh[r][:]  (bf16)
__global__ void cast_wstep(const float* __restrict__ W_ih, const float* __restrict__ W_hh,
                           unsigned short* __restrict__ Wstep) {
  int r = blockIdx.x, c = threadIdx.x * 4;
  float4 a = *(const float4*)&W_ih[(size_t)r * 1536 + 512 + c];
  float4 h = *(const float4*)&W_hh[(size_t)r * 1024 + c];
  us4 va; va[0] = f2bf(a.x); va[1] = f2bf(a.y); va[2] = f2bf(a.z); va[3] = f2bf(a.w);
  us4 vh; vh[0] = f2bf(h.x); vh[1] = f2bf(h.y); vh[2] = f2bf(h.z); vh[3] = f2bf(h.w);
  *(us4*)&Wstep[(size_t)r * 2048 + c]        = va;
  *(us4*)&Wstep[(size_t)r * 2048 + 1024 + c] = vh;
}

// ---------------- W_out f32 -> bf16 (optional, ws-size permitting)
__global__ void cast_wout(const float* __restrict__ W, unsigned short* __restrict__ Wb) {
  size_t i = ((size_t)blockIdx.x * 256 + threadIdx.x) * 4;
  float4 f = *(const float4*)&W[i];
  us4 v; v[0] = f2bf(f.x); v[1] = f2bf(f.y); v[2] = f2bf(f.z); v[3] = f2bf(f.w);
  *(us4*)&Wb[i] = v;
}

// ---------------- MFMA GEMM: C[M][N] = A[M][K](bf16) @ B[N][K]^T + biases
// tile 128x128, BK=64, 4 waves (2x2). XOR-swizzled LDS, XCD-chunked remap.
// mode 0: C[m*ldc + n]   mode 1: C[((m&31)*64 + (m>>5))*ldc + n]
__global__ __launch_bounds__(256) void gemm_bb(
    const unsigned short* __restrict__ A, int lda,
    const void* __restrict__ Bv, int ldb, int bfmt,
    float* __restrict__ C, int ldc,
    const float* __restrict__ bias1, const float* __restrict__ bias2,
    int K, int mode) {
  __shared__ unsigned short sA[128 * 64];
  __shared__ unsigned short sB[128 * 64];
  const int tid = threadIdx.x;
  const int nwg  = gridDim.x * gridDim.y;     // must be % 8 == 0 (4000, 512 ok)
  const int flat = blockIdx.y * gridDim.x + blockIdx.x;
  const int u    = (flat & 7) * (nwg >> 3) + (flat >> 3);
  const int by   = u % gridDim.y;
  const int bx   = u / gridDim.y;
  const int n0 = bx * 128, m0 = by * 128;
  const int w = tid >> 6, l = tid & 63;
  const int wm = w >> 1, wn = w & 1;
  const int l15 = l & 15, q = l >> 4;
  const int xs = (l15 & 7) << 3;
  const int gr = l >> 3;               // glds: row within inst (8 rows x 64B per inst)
  const int gk = (l & 7) << 3;         // glds: short offset within row

  floatx4 acc[4][4];
  #pragma unroll
  for (int i = 0; i < 4; ++i)
    #pragma unroll
    for (int j = 0; j < 4; ++j) acc[i][j] = (floatx4){0.f, 0.f, 0.f, 0.f};

  for (int k0 = 0; k0 < K; k0 += 64) {
    __syncthreads();
    #pragma unroll
    for (int p = 0; p < 4; ++p) {
      int inst = w * 4 + p;
      int row = inst * 8 + gr;
      int kk = gk ^ ((row & 7) << 3);       // inverse-swizzled global source
      glds16(&A[(size_t)(m0 + row) * lda + k0 + kk], &sA[inst * 512]);
    }
    if (bfmt) {
      const unsigned short* Bw = (const unsigned short*)Bv;
      #pragma unroll
      for (int p = 0; p < 4; ++p) {
        int inst = w * 4 + p;
        int row = inst * 8 + gr;
        int kk = gk ^ ((row & 7) << 3);
        glds16(&Bw[(size_t)(n0 + row) * ldb + k0 + kk], &sB[inst * 512]);
      }
    } else {
      const float* Bw = (const float*)Bv;
      #pragma unroll
      for (int p = 0; p < 8; ++p) {
        int idx4 = p * 256 + tid;
        int row = idx4 >> 4, kc = (idx4 & 15) << 2;
        float4 f = *(const float4*)&Bw[(size_t)(n0 + row) * ldb + k0 + kc];
        us4 v; v[0] = f2bf(f.x); v[1] = f2bf(f.y); v[2] = f2bf(f.z); v[3] = f2bf(f.w);
        *(us4*)&sB[row * 64 + (kc ^ ((row & 7) << 3))] = v;
      }
    }
    __syncthreads();
    #pragma unroll
    for (int kk2 = 0; kk2 < 2; ++kk2) {
      const int kr = (kk2 * 32 + q * 8) ^ xs;
      short8 af[4], bf8[4];
      #pragma unroll
      for (int mt = 0; mt < 4; ++mt)
        af[mt] = *(short8*)&sA[(wm * 64 + mt * 16 + l15) * 64 + kr];
      #pragma unroll
      for (int nt = 0; nt < 4; ++nt)
        bf8[nt] = *(short8*)&sB[(wn * 64 + nt * 16 + l15) * 64 + kr];
      #pragma unroll
      for (int mt = 0; mt < 4; ++mt)
        #pragma unroll
        for (int nt = 0; nt < 4; ++nt)
          acc[mt][nt] = __builtin_amdgcn_mfma_f32_16x16x32_bf16(af[mt], bf8[nt], acc[mt][nt], 0, 0, 0);
    }
  }

  #pragma unroll
  for (int mt = 0; mt < 4; ++mt)
    #pragma unroll
    for (int nt = 0; nt < 4; ++nt)
      #pragma unroll
      for (int r = 0; r < 4; ++r) {
        int m = m0 + wm * 64 + mt * 16 + q * 4 + r;
        int n = n0 + wn * 64 + nt * 16 + l15;
        float v = acc[mt][nt][r];
        if (bias1) v += bias1[n];
        if (bias2) v += bias2[n];
        if (mode == 0) {
          C[(size_t)m * ldc + n] = v;
        } else {
          int b = m & 31, t = m >> 5;
          C[(size_t)(b * 64 + t) * ldc + n] = v;
        }
      }
}

// ---------------- persistent recurrence with per-step ring buffers.
// xring[t] (bf16 [32][2048]) = ctx(t) | h(t-1); hring[t] (f32 [32][1024]) = h(t-1).
// Writers use sc0sc1 stores (coherence point); readers use NORMAL cached loads —
// each slot address is fresh per step, so L2 can never be stale, and same-XCD
// blocks share the L2 copy. Barrier = per-block arrival slots, no atomics.
__global__ __launch_bounds__(256, 1) void recurrence(
    const unsigned short* __restrict__ enc_bf, float* __restrict__ cbuf,
    unsigned short* __restrict__ xring, float* __restrict__ hring,
    const unsigned short* __restrict__ Wstep, const float* __restrict__ gw,
    unsigned short* __restrict__ hs, const int* __restrict__ slen,
    unsigned int* __restrict__ slots) {
  __shared__ unsigned short wlds[16 * 2048];   // 64 KB: this block's 16 gate rows (swizzled)
  __shared__ float red[2048];                  // gates cross-wave reduction
  __shared__ float esh[64];
  __shared__ float ashp[64];

  const int tid = threadIdx.x;
  const int w = tid >> 6, l = tid & 63;
  const int l15 = l & 15, q = l >> 4;
  // XCD-aligned unit ownership: blocks on one XCD (bid%8 fixed) cover contiguous units
  const int u0 = (((blockIdx.x & 7) << 5) | (blockIdx.x >> 3)) << 2;

  // one-time: stage this block's 16 Wstep gate rows into LDS with XOR swizzle
  #pragma unroll
  for (int ii = 0; ii < 16; ++ii) {
    int idx = ii * 256 + tid;
    int n = idx >> 8;
    int kc = (idx & 255) << 3;
    int rn = (n >> 2) * 1024 + u0 + (n & 3);
    short8 v = *(const short8*)&Wstep[(size_t)rn * 2048 + kc];
    *(short8*)&wlds[n * 2048 + (kc ^ ((n & 7) << 3))] = v;
  }

  const int lenb = (blockIdx.x < 32) ? slen[blockIdx.x] : 0;
  float creg = (tid < 128) ? cbuf[(tid >> 2) * 1024 + u0 + (tid & 3)] : 0.f;

  for (int t = 0; t < 64; ++t) {
    const unsigned short* xc = xring + (size_t)t * 65536;        // ctx(t) | h(t-1)
    unsigned short*       xn = xring + (size_t)(t + 1) * 65536;  // h(t) -> half
    const float*        hcur = hring + (size_t)t * 32768;        // h(t-1) f32
    float*               hnx = hring + (size_t)(t + 1) * 32768;

    // prefetch gw (word-part gates) + issue early; used in the tail
    float gp0 = 0.f, gp1 = 0.f, gp2 = 0.f, gp3 = 0.f;
    if (tid < 128) {
      const float* gp = &gw[(size_t)(t * 32 + (tid >> 2)) * 4096 + u0 + (tid & 3)];
      gp0 = gp[0]; gp1 = gp[1024]; gp2 = gp[2048]; gp3 = gp[3072];
    }

    // ---- attention (blocks 0..31), bf16 enc, h in registers
    if (blockIdx.x < 32) {
      const int b = blockIdx.x;
      const float* hb = &hcur[b * 1024];
      float4 h0v = *(const float4*)&hb[l * 8];
      float4 h1v = *(const float4*)&hb[l * 8 + 4];
      float4 h2v = *(const float4*)&hb[512 + l * 8];
      float4 h3v = *(const float4*)&hb[512 + l * 8 + 4];
      const unsigned short* ebase = &enc_bf[(size_t)b * 65536];
      for (int si = 0; si < 16; ++si) {
        int s = w * 16 + si;
        const unsigned short* er = ebase + (size_t)s * 1024;
        short8 e0 = *(const short8*)&er[l * 8];
        short8 e1 = *(const short8*)&er[512 + l * 8];
        float v = bf2f(e0[0]) * h0v.x + bf2f(e0[1]) * h0v.y +
                  bf2f(e0[2]) * h0v.z + bf2f(e0[3]) * h0v.w +
                  bf2f(e0[4]) * h1v.x + bf2f(e0[5]) * h1v.y +
                  bf2f(e0[6]) * h1v.z + bf2f(e0[7]) * h1v.w +
                  bf2f(e1[0]) * h2v.x + bf2f(e1[1]) * h2v.y +
                  bf2f(e1[2]) * h2v.z + bf2f(e1[3]) * h2v.w +
                  bf2f(e1[4]) * h3v.x + bf2f(e1[5]) * h3v.y +
                  bf2f(e1[6]) * h3v.z + bf2f(e1[7]) * h3v.w;
        #pragma unroll
        for (int off = 32; off; off >>= 1) v += __shfl_down(v, off);
        if (l == 0) esh[s] = v;
      }
      __syncthreads();
      if (tid < 64) {
        float e = (tid < lenb) ? esh[tid] : -1e30f;
        float m = e;
        #pragma unroll
        for (int off = 32; off; off >>= 1) m = fmaxf(m, __shfl_down(m, off));
        m = __shfl(m, 0);
        float p = (tid < lenb) ? __expf(e - m) : 0.f;
        float s = p;
        #pragma unroll
        for (int off = 32; off; off >>= 1) s += __shfl_down(s, off);
        s = __shfl(s, 0);
        ashp[tid] = p / s;
      }
      __syncthreads();
      // ctx: thread tid owns d = tid*4..+3
      float4 acc = {0, 0, 0, 0};
      const unsigned short* eb = &enc_bf[(size_t)b * 65536 + tid * 4];
      #pragma unroll 8
      for (int s = 0; s < 64; ++s) {
        float a = ashp[s];
        us4 ev = *(const us4*)&eb[(size_t)s * 1024];
        acc.x += a * bf2f((short)ev[0]); acc.y += a * bf2f((short)ev[1]);
        acc.z += a * bf2f((short)ev[2]); acc.w += a * bf2f((short)ev[3]);
      }
      us4 v; v[0] = f2bf(acc.x); v[1] = f2bf(acc.y); v[2] = f2bf(acc.z); v[3] = f2bf(acc.w);
      astore8((unsigned short*)&xc[b * 2048 + tid * 4], v);   // ctx half of slot t
    }
    gridbar(slots, (unsigned)(2 * t + 1));

    // ---- gates + LSTM update (x from L2-cached ring slot, W from LDS)
    {
      floatx4 acc0 = (floatx4){0.f, 0.f, 0.f, 0.f};
      floatx4 acc1 = (floatx4){0.f, 0.f, 0.f, 0.f};
      const int kbase = w * 512;
      #pragma unroll
      for (int ks = 0; ks < 16; ++ks) {
        int k0 = kbase + ks * 32 + q * 8;
        short8 b8 = *(short8*)&wlds[l15 * 2048 + (k0 ^ ((l15 & 7) << 3))];
        short8 a0 = *(const short8*)&xc[(size_t)l15 * 2048 + k0];
        short8 a1 = *(const short8*)&xc[(size_t)(16 + l15) * 2048 + k0];
        acc0 = __builtin_amdgcn_mfma_f32_16x16x32_bf16(a0, b8, acc0, 0, 0, 0);
        acc1 = __builtin_amdgcn_mfma_f32_16x16x32_bf16(a1, b8, acc1, 0, 0, 0);
      }
      #pragma unroll
      for (int r = 0; r < 4; ++r) {
        red[w * 512 + (q * 4 + r) * 16 + l15]      = acc0[r];
        red[w * 512 + (16 + q * 4 + r) * 16 + l15] = acc1[r];
      }
      __syncthreads();
      if (tid < 128) {
        int bb = tid >> 2, ui = tid & 3;
        int uu = u0 + ui;
        float g4[4];
        #pragma unroll
        for (int g = 0; g < 4; ++g) {
          int n = g * 4 + ui;
          g4[g] = red[bb * 16 + n] + red[512 + bb * 16 + n] +
                  red[1024 + bb * 16 + n] + red[1536 + bb * 16 + n];
        }
        g4[0] += gp0; g4[1] += gp1; g4[2] += gp2; g4[3] += gp3;
        float fi = sigf(g4[0]);
        float ff = sigf(g4[1]);
        float gg = tanhf(g4[2]);
        float fo = sigf(g4[3]);
        float cn = ff * creg + fi * gg;
        creg = cn;
        float hn = fo * tanhf(cn);
        astoref(&hnx[bb * 1024 + uu], hn);              // h(t) f32 -> slot t+1
        unsigned short hb16 = f2bf(hn);
        hs[(size_t)(t * 32 + bb) * 1024 + uu] = hb16;   // read by next launch
        // pack this bb's 4 units into one 8B coherent store
        unsigned hv = (unsigned)hb16;
        unsigned p0 = __shfl(hv, (l & ~3) + 0);
        unsigned p1 = __shfl(hv, (l & ~3) + 1);
        unsigned p2 = __shfl(hv, (l & ~3) + 2);
        unsigned p3 = __shfl(hv, (l & ~3) + 3);
        if (ui == 0) {
          unsigned long long pk = (unsigned long long)p0 |
                                  ((unsigned long long)p1 << 16) |
                                  ((unsigned long long)p2 << 32) |
                                  ((unsigned long long)p3 << 48);
          __hip_atomic_store((unsigned long long*)&xn[bb * 2048 + 1024 + u0], pk,
                             __ATOMIC_RELAXED, AGENT);
        }
      }
    }
    if (t != 63) gridbar(slots, (unsigned)(2 * t + 2));
  }
}

extern "C" void kernel_launch(void* const* d_in, const int* in_sizes, int n_in,
                              void* d_out, int out_size, void* d_ws, size_t ws_size,
                              hipStream_t stream) {
  const int*   ts     = (const int*)d_in[0];    // target_sentences [B,T]
  const int*   slen   = (const int*)d_in[2];    // source_lengths [B]
  const int*   ss     = (const int*)d_in[3];    // source_sentences [B,S]
  const int*   pp     = (const int*)d_in[4];    // positions [B,S]
  const float* enc_emb = (const float*)d_in[8];
  const float* pos_emb = (const float*)d_in[9];
  const float* dec_emb = (const float*)d_in[10];
  const float* W_h0   = (const float*)d_in[11];
  const float* b_h0   = (const float*)d_in[12];
  const float* W_ih   = (const float*)d_in[13];
  const float* W_hh   = (const float*)d_in[14];
  const float* b_ih   = (const float*)d_in[15];
  const float* b_hh   = (const float*)d_in[16];
  const float* W_out  = (const float*)d_in[17];
  const float* b_out  = (const float*)d_in[18];
  float* out = (float*)d_out;

  // ---- workspace carve-up (persistent across recurrence)
  char* base = (char*)d_ws;
  size_t off = 0;
  auto carve = [&](size_t bytes) { void* p = base + off; off += (bytes + 255) & ~(size_t)255; return p; };
  float*          enc      = (float*)carve((size_t)B_ * S_ * 1024 * 4);      // 8.39 MB
  float*          em       = (float*)carve((size_t)B_ * 1024 * 4);
  float*          cbuf     = (float*)carve((size_t)B_ * 1024 * 4);
  unsigned short* words_bf = (unsigned short*)carve((size_t)2048 * E_ * 2);  // 2.10 MB
  unsigned short* Wstep    = (unsigned short*)carve((size_t)4096 * 2048 * 2);// 16.8 MB
  float*          gw       = (float*)carve((size_t)2048 * 4096 * 4);         // 33.6 MB
  unsigned short* hs       = (unsigned short*)carve((size_t)2048 * 1024 * 2);// 4.19 MB
  unsigned int*   bar      = (unsigned int*)carve(1024);                     // 256 slots
  unsigned short* Wob      = (unsigned short*)carve((size_t)VT_ * 1024 * 2); // 65.5 MB (optional)
  const bool haveWob = (off <= ws_size);

  // ---- scratch inside d_out (262 MB; fully overwritten by the final GEMM)
  char* ob = (char*)d_out;
  unsigned short* enc_bf = (unsigned short*)(ob);                    // 4.19 MB
  unsigned short* xring  = (unsigned short*)(ob + 4194304);          // 65 x 128 KiB
  float*          hring  = (float*)(ob + 4194304 + 8519680);         // 65 x 128 KiB

  hipMemsetAsync(bar, 0, 1024, stream);

  // ---- prep (order enforced by stream)
  build_enc  <<<B_ * S_, 256, 0, stream>>>(ss, pp, enc_emb, pos_emb, enc, enc_bf);
  enc_mean   <<<B_,      256, 0, stream>>>(enc, em);
  h0_kernel  <<<(B_ * H_) / 4, 256, 0, stream>>>(em, W_h0, b_h0, cbuf, hring, xring);
  build_words<<<B_ * T_, 256, 0, stream>>>(ts, dec_emb, words_bf);
  cast_wstep <<<4096,    256, 0, stream>>>(W_ih, W_hh, Wstep);
  if (haveWob) cast_wout<<<VT_, 256, 0, stream>>>(W_out, Wob);

  // gw = words @ W_ih[:, :512]^T + b_ih + b_hh    (M=2048, N=4096, K=512; B = f32 W_ih)
  gemm_bb<<<dim3(4096 / 128, 2048 / 128), 256, 0, stream>>>(
      words_bf, E_, (const void*)W_ih, 1536, 0, gw, 4096, b_ih, b_hh, E_, 0);

  // ---- full recurrence in one persistent kernel (64 steps, 2 slot-barriers/step)
  recurrence<<<256, 256, 0, stream>>>(enc_bf, cbuf, xring, hring, Wstep, gw, hs, slen, bar);

  // ---- out = hs @ W_out^T + b_out  (M=2048, N=32000, K=1024), remapped to [B,T,V]
  gemm_bb<<<dim3(VT_ / 128, 2048 / 128), 256, 0, stream>>>(
      hs, H_, haveWob ? (const void*)Wob : (const void*)W_out, H_, haveWob ? 1 : 0,
      out, VT_, b_out, nullptr, H_, 1);
}